// Round 1
// baseline (3552.740 us; speedup 1.0000x reference)
//
#include <hip/hip_runtime.h>
#include <hip/hip_bf16.h>

#define SEQ 16384
#define DIM 1280
#define NHEAD 16
#define HD 80
#define WIN 64
#define NWIN 256   // SEQ / WIN
#define QKV_N 3840 // 3 * DIM

// ---------------------------------------------------------------------------
// Tiled f32 GEMM:  out[M][N] = X[M][K] @ Wt[N][K]^T + bias[N]
// 64x64 tile, BK=16, 256 threads, 4x4 per thread, K-major LDS (float4 frags)
// ---------------------------------------------------------------------------
__global__ __launch_bounds__(256) void gemm_nt_bias_f32(
    const float* __restrict__ X,
    const float* __restrict__ Wt,
    const float* __restrict__ bias,
    float* __restrict__ out,
    int M, int N, int K)
{
    __shared__ float xs[16][68];  // [k][row], stride 68 keeps float4 alignment
    __shared__ float ws[16][68];

    const int t = threadIdx.x;
    const int tx = t & 15;        // output col group
    const int ty = t >> 4;        // output row group
    const int bm = blockIdx.y * 64;
    const int bn = blockIdx.x * 64;

    const int lrow = t >> 2;          // 0..63
    const int lk   = (t & 3) * 4;     // 0,4,8,12

    const float* xp = X  + (size_t)(bm + lrow) * K + lk;
    const float* wp = Wt + (size_t)(bn + lrow) * K + lk;

    float acc[4][4] = {};

    for (int k0 = 0; k0 < K; k0 += 16) {
        float4 xa = *(const float4*)(xp + k0);
        float4 wa = *(const float4*)(wp + k0);
        __syncthreads();
        xs[lk + 0][lrow] = xa.x; xs[lk + 1][lrow] = xa.y;
        xs[lk + 2][lrow] = xa.z; xs[lk + 3][lrow] = xa.w;
        ws[lk + 0][lrow] = wa.x; ws[lk + 1][lrow] = wa.y;
        ws[lk + 2][lrow] = wa.z; ws[lk + 3][lrow] = wa.w;
        __syncthreads();
#pragma unroll
        for (int kk = 0; kk < 16; ++kk) {
            float4 a = *(const float4*)&xs[kk][ty * 4];
            float4 b = *(const float4*)&ws[kk][tx * 4];
            acc[0][0] += a.x * b.x; acc[0][1] += a.x * b.y; acc[0][2] += a.x * b.z; acc[0][3] += a.x * b.w;
            acc[1][0] += a.y * b.x; acc[1][1] += a.y * b.y; acc[1][2] += a.y * b.z; acc[1][3] += a.y * b.w;
            acc[2][0] += a.z * b.x; acc[2][1] += a.z * b.y; acc[2][2] += a.z * b.z; acc[2][3] += a.z * b.w;
            acc[3][0] += a.w * b.x; acc[3][1] += a.w * b.y; acc[3][2] += a.w * b.z; acc[3][3] += a.w * b.w;
        }
    }

    float4 bv = *(const float4*)&bias[bn + tx * 4];
#pragma unroll
    for (int i = 0; i < 4; ++i) {
        float4 o;
        o.x = acc[i][0] + bv.x; o.y = acc[i][1] + bv.y;
        o.z = acc[i][2] + bv.z; o.w = acc[i][3] + bv.w;
        *(float4*)&out[(size_t)(bm + ty * 4 + i) * N + bn + tx * 4] = o;
    }
}

// ---------------------------------------------------------------------------
// Windowed attention, one block per (head, window).
// qkv layout: [S][3840] = [S][{q,k,v} x 16 heads x 80]
// Applies RoPE (+1/sqrt(80) on q), scores+mask, row softmax, PV.
// ---------------------------------------------------------------------------
__global__ __launch_bounds__(256) void win_attn_f32(
    const float* __restrict__ qkv,
    const float* __restrict__ cosb,   // [S][80]
    const float* __restrict__ sinb,   // [S][80]
    const float* __restrict__ mask,   // [NWIN][64][64]
    float* __restrict__ attn_out)     // [S][1280]
{
    const int h = blockIdx.x;   // 0..15
    const int b = blockIdx.y;   // 0..255
    const int t = threadIdx.x;

    __shared__ float q[64][81];
    __shared__ float k[64][81];
    __shared__ float v[64][81];
    __shared__ float sc[64][65];

    // load raw q,k,v tiles
    for (int e = t; e < 64 * HD; e += 256) {
        const int i = e / HD, d = e % HD;
        const size_t base = (size_t)(b * 64 + i) * QKV_N + h * HD + d;
        q[i][d] = qkv[base];
        k[i][d] = qkv[base + DIM];
        v[i][d] = qkv[base + 2 * DIM];
    }
    __syncthreads();

    // RoPE in-place (each pair owned by exactly one thread)
    const float scale = 0.11180339887498949f;  // 1/sqrt(80)
    for (int e = t; e < 64 * 40; e += 256) {
        const int i = e / 40, d = e % 40;
        const int tok = b * 64 + i;
        const float c1 = cosb[tok * HD + d],      s1 = sinb[tok * HD + d];
        const float c2 = cosb[tok * HD + d + 40], s2 = sinb[tok * HD + d + 40];
        const float q1 = q[i][d], q2 = q[i][d + 40];
        q[i][d]      = (q1 * c1 - q2 * s1) * scale;
        q[i][d + 40] = (q2 * c2 + q1 * s2) * scale;
        const float k1 = k[i][d], k2 = k[i][d + 40];
        k[i][d]      = k1 * c1 - k2 * s1;
        k[i][d + 40] = k2 * c2 + k1 * s2;
    }
    __syncthreads();

    // scores + mask
    for (int e = t; e < 64 * 64; e += 256) {
        const int i = e >> 6, j = e & 63;
        float s = 0.f;
#pragma unroll 8
        for (int d = 0; d < HD; ++d) s += q[i][d] * k[j][d];
        sc[i][j] = s + mask[(size_t)b * 4096 + i * 64 + j];
    }
    __syncthreads();

    // row softmax (threads 0..63, one row each)
    if (t < 64) {
        float m = -1e30f;
#pragma unroll 8
        for (int j = 0; j < 64; ++j) m = fmaxf(m, sc[t][j]);
        float sum = 0.f;
#pragma unroll 8
        for (int j = 0; j < 64; ++j) {
            const float p = __expf(sc[t][j] - m);
            sc[t][j] = p;
            sum += p;
        }
        const float inv = 1.0f / sum;
#pragma unroll 8
        for (int j = 0; j < 64; ++j) sc[t][j] *= inv;
    }
    __syncthreads();

    // PV
    for (int e = t; e < 64 * HD; e += 256) {
        const int i = e / HD, d = e % HD;
        float s = 0.f;
#pragma unroll 8
        for (int j = 0; j < 64; ++j) s += sc[i][j] * v[j][d];
        attn_out[(size_t)(b * 64 + i) * DIM + h * HD + d] = s;
    }
}

// ---------------------------------------------------------------------------
extern "C" void kernel_launch(void* const* d_in, const int* in_sizes, int n_in,
                              void* d_out, int out_size, void* d_ws, size_t ws_size,
                              hipStream_t stream) {
    const float* hidden = (const float*)d_in[0];
    const float* masks  = (const float*)d_in[1];
    const float* cosb   = (const float*)d_in[2];
    const float* sinb   = (const float*)d_in[3];
    const float* qkv_w  = (const float*)d_in[4];
    const float* qkv_b  = (const float*)d_in[5];
    const float* proj_w = (const float*)d_in[6];
    const float* proj_b = (const float*)d_in[7];
    float* out = (float*)d_out;

    float* qkv  = (float*)d_ws;                         // [SEQ][3840] = 251.7 MB
    float* attn = qkv + (size_t)SEQ * QKV_N;            // [SEQ][1280] =  83.9 MB

    // 1) fused QKV projection + bias
    {
        dim3 grid(QKV_N / 64, SEQ / 64);
        gemm_nt_bias_f32<<<grid, 256, 0, stream>>>(hidden, qkv_w, qkv_b, qkv,
                                                   SEQ, QKV_N, DIM);
    }
    // 2) windowed attention (RoPE fused at load)
    {
        dim3 grid(NHEAD, NWIN);
        win_attn_f32<<<grid, 256, 0, stream>>>(qkv, cosb, sinb, masks, attn);
    }
    // 3) output projection + bias
    {
        dim3 grid(DIM / 64, SEQ / 64);
        gemm_nt_bias_f32<<<grid, 256, 0, stream>>>(attn, proj_w, proj_b, out,
                                                   SEQ, DIM, DIM);
    }
}

// Round 2
// 750.524 us; speedup vs baseline: 4.7337x; 4.7337x over previous
//
#include <hip/hip_runtime.h>
#include <hip/hip_bf16.h>

#define SEQ 16384
#define DIM 1280
#define NHEAD 16
#define HD 80
#define NWIN 256   // SEQ / 64
#define QKV_N 3840 // 3 * DIM

typedef __attribute__((ext_vector_type(8))) short bf16x8;
typedef __attribute__((ext_vector_type(8))) unsigned short ushort8;
typedef __attribute__((ext_vector_type(4))) float f32x4;

__device__ inline unsigned short f2bf(float x) {
    union { __hip_bfloat16 b; unsigned short u; } cv;
    cv.b = __float2bfloat16(x);
    return cv.u;
}
__device__ inline float bf2f(unsigned short u) {
    union { unsigned int i; float f; } cv;
    cv.i = ((unsigned int)u) << 16;
    return cv.f;
}

// async global->LDS, 16B per lane, wave-uniform LDS base + lane*16
#define GLD16(g, l) __builtin_amdgcn_global_load_lds( \
    (const __attribute__((address_space(1))) void*)(g), \
    (__attribute__((address_space(3))) void*)(l), 16, 0, 0)

// ---------------------------------------------------------------------------
// f32 -> bf16 convert, 8 elems/thread, vectorized
// ---------------------------------------------------------------------------
__global__ __launch_bounds__(256) void cvt_f32_bf16(const float* __restrict__ src,
                                                    unsigned short* __restrict__ dst,
                                                    long n) {
    long i = ((long)blockIdx.x * 256 + threadIdx.x) * 8;
    if (i >= n) return;
    const float4 a = *(const float4*)(src + i);
    const float4 b = *(const float4*)(src + i + 4);
    ushort8 o;
    o[0] = f2bf(a.x); o[1] = f2bf(a.y); o[2] = f2bf(a.z); o[3] = f2bf(a.w);
    o[4] = f2bf(b.x); o[5] = f2bf(b.y); o[6] = f2bf(b.z); o[7] = f2bf(b.w);
    *(ushort8*)(dst + i) = o;
}

// ---------------------------------------------------------------------------
// bf16 MFMA NT-GEMM: out[M][N] = A[M][K] @ B[N][K]^T + bias
// 128x128 tile, BK=32, 256 threads (4 waves, 2x2), mfma_f32_16x16x32_bf16
// global_load_lds width-16 staging; K-major LDS tiles -> ds_read_b128 frags
// ---------------------------------------------------------------------------
template <int OUT_BF16>
__global__ __launch_bounds__(256) void gemm_nt_bf16(
    const unsigned short* __restrict__ A,   // [M][K] bf16
    const unsigned short* __restrict__ B,   // [N][K] bf16
    const float* __restrict__ bias,         // [N]
    void* __restrict__ outp,                // [M][N] f32 or bf16
    int M, int N, int K)
{
    __shared__ unsigned short As[128 * 32];
    __shared__ unsigned short Bs[128 * 32];

    const int t = threadIdx.x;
    const int lane = t & 63;
    const int bm = blockIdx.y * 128;
    const int bn = blockIdx.x * 128;
    const int wave = t >> 6;
    const int wr = (wave >> 1) * 64;   // wave's 64x64 sub-tile
    const int wc = (wave & 1) * 64;

    // staging: chunk c = t + 256*i covers LDS bytes [c*16, c*16+16)
    // row = c>>2 (since 32 bf16 per row = 4 chunks), koff = (c&3)*8 elems
    const int r0 = t >> 2;
    const int koff = (t & 3) * 8;
    const unsigned short* ga0 = A + (size_t)(bm + r0) * K + koff;
    const unsigned short* ga1 = A + (size_t)(bm + r0 + 64) * K + koff;
    const unsigned short* gb0 = B + (size_t)(bn + r0) * K + koff;
    const unsigned short* gb1 = B + (size_t)(bn + r0 + 64) * K + koff;

    unsigned short* lA0 = As + (t & ~63) * 8;  // wave-uniform base (bytes: *16)
    unsigned short* lA1 = lA0 + 2048;          // +4096 B
    unsigned short* lB0 = Bs + (t & ~63) * 8;
    unsigned short* lB1 = lB0 + 2048;

    // MFMA fragment addresses: lane holds row (lane&15), k [(lane>>4)*8, +8)
    const int row16 = lane & 15;
    const int kb8 = (lane >> 4) * 8;
    const unsigned short* pa = As + (wr + row16) * 32 + kb8;
    const unsigned short* pb = Bs + (wc + row16) * 32 + kb8;

    f32x4 acc[4][4];
#pragma unroll
    for (int m = 0; m < 4; ++m)
#pragma unroll
        for (int n = 0; n < 4; ++n)
            acc[m][n] = (f32x4){0.f, 0.f, 0.f, 0.f};

    for (int k0 = 0; k0 < K; k0 += 32) {
        __syncthreads();                 // previous iter's ds_reads done
        GLD16(ga0 + k0, lA0);
        GLD16(ga1 + k0, lA1);
        GLD16(gb0 + k0, lB0);
        GLD16(gb1 + k0, lB1);
        __syncthreads();                 // vmcnt(0) drain -> staged data visible

        bf16x8 af[4], bf[4];
#pragma unroll
        for (int m = 0; m < 4; ++m) af[m] = *(const bf16x8*)(pa + m * 512);
#pragma unroll
        for (int n = 0; n < 4; ++n) bf[n] = *(const bf16x8*)(pb + n * 512);
#pragma unroll
        for (int m = 0; m < 4; ++m)
#pragma unroll
            for (int n = 0; n < 4; ++n)
                acc[m][n] = __builtin_amdgcn_mfma_f32_16x16x32_bf16(
                    af[m], bf[n], acc[m][n], 0, 0, 0);
    }

    // C/D layout: col = lane&15, row = (lane>>4)*4 + reg   [m89-verified]
    const int or0 = bm + wr + (lane >> 4) * 4;
    const int oc0 = bn + wc + row16;
    float bv[4];
#pragma unroll
    for (int n = 0; n < 4; ++n) bv[n] = bias[oc0 + n * 16];
#pragma unroll
    for (int m = 0; m < 4; ++m)
#pragma unroll
        for (int n = 0; n < 4; ++n)
#pragma unroll
            for (int r = 0; r < 4; ++r) {
                const int row = or0 + m * 16 + r;
                const int col = oc0 + n * 16;
                const float v = acc[m][n][r] + bv[n];
                if (OUT_BF16)
                    ((unsigned short*)outp)[(size_t)row * N + col] = f2bf(v);
                else
                    ((float*)outp)[(size_t)row * N + col] = v;
            }
}

// ---------------------------------------------------------------------------
// Windowed attention, one block per (head, window). bf16 in/out, f32 compute.
// ---------------------------------------------------------------------------
__global__ __launch_bounds__(256) void win_attn(
    const unsigned short* __restrict__ qkv,  // [S][3840] bf16
    const float* __restrict__ cosb,          // [S][80]
    const float* __restrict__ sinb,          // [S][80]
    const float* __restrict__ mask,          // [NWIN][64][64]
    unsigned short* __restrict__ attn_out)   // [S][1280] bf16
{
    const int h = blockIdx.x;
    const int b = blockIdx.y;
    const int t = threadIdx.x;

    __shared__ float q[64][81];
    __shared__ float k[64][81];
    __shared__ float v[64][81];
    __shared__ float sc[64][65];

    // vectorized bf16 loads: 80 elems = 10 chunks of 8
    for (int e = t; e < 64 * 10; e += 256) {
        const int i = e / 10, d = (e % 10) * 8;
        const size_t base = (size_t)(b * 64 + i) * QKV_N + h * HD + d;
        const bf16x8 qv = *(const bf16x8*)(qkv + base);
        const bf16x8 kv = *(const bf16x8*)(qkv + base + DIM);
        const bf16x8 vv = *(const bf16x8*)(qkv + base + 2 * DIM);
#pragma unroll
        for (int j = 0; j < 8; ++j) {
            q[i][d + j] = bf2f((unsigned short)qv[j]);
            k[i][d + j] = bf2f((unsigned short)kv[j]);
            v[i][d + j] = bf2f((unsigned short)vv[j]);
        }
    }
    __syncthreads();

    // RoPE in-place (+1/sqrt(80) folded into q)
    const float scale = 0.11180339887498949f;
    for (int e = t; e < 64 * 40; e += 256) {
        const int i = e / 40, d = e % 40;
        const int tok = b * 64 + i;
        const float c1 = cosb[tok * HD + d],      s1 = sinb[tok * HD + d];
        const float c2 = cosb[tok * HD + d + 40], s2 = sinb[tok * HD + d + 40];
        const float q1 = q[i][d], q2 = q[i][d + 40];
        q[i][d]      = (q1 * c1 - q2 * s1) * scale;
        q[i][d + 40] = (q2 * c2 + q1 * s2) * scale;
        const float k1 = k[i][d], k2 = k[i][d + 40];
        k[i][d]      = k1 * c1 - k2 * s1;
        k[i][d + 40] = k2 * c2 + k1 * s2;
    }
    __syncthreads();

    // scores + mask
    for (int e = t; e < 64 * 64; e += 256) {
        const int i = e >> 6, j = e & 63;
        float s = 0.f;
#pragma unroll 8
        for (int d = 0; d < HD; ++d) s += q[i][d] * k[j][d];
        sc[i][j] = s + mask[(size_t)b * 4096 + i * 64 + j];
    }
    __syncthreads();

    // row softmax
    if (t < 64) {
        float m = -1e30f;
#pragma unroll 8
        for (int j = 0; j < 64; ++j) m = fmaxf(m, sc[t][j]);
        float sum = 0.f;
#pragma unroll 8
        for (int j = 0; j < 64; ++j) {
            const float p = __expf(sc[t][j] - m);
            sc[t][j] = p;
            sum += p;
        }
        const float inv = 1.0f / sum;
#pragma unroll 8
        for (int j = 0; j < 64; ++j) sc[t][j] *= inv;
    }
    __syncthreads();

    // PV, write bf16
    for (int e = t; e < 64 * HD; e += 256) {
        const int i = e / HD, d = e % HD;
        float s = 0.f;
#pragma unroll 8
        for (int j = 0; j < 64; ++j) s += sc[i][j] * v[j][d];
        attn_out[(size_t)(b * 64 + i) * DIM + h * HD + d] = f2bf(s);
    }
}

// ---------------------------------------------------------------------------
extern "C" void kernel_launch(void* const* d_in, const int* in_sizes, int n_in,
                              void* d_out, int out_size, void* d_ws, size_t ws_size,
                              hipStream_t stream) {
    const float* hidden = (const float*)d_in[0];
    const float* masks  = (const float*)d_in[1];
    const float* cosb   = (const float*)d_in[2];
    const float* sinb   = (const float*)d_in[3];
    const float* qkv_w  = (const float*)d_in[4];
    const float* qkv_b  = (const float*)d_in[5];
    const float* proj_w = (const float*)d_in[6];
    const float* proj_b = (const float*)d_in[7];
    float* out = (float*)d_out;

    // workspace (bf16), ~223 MB total
    unsigned short* qkv_bf    = (unsigned short*)d_ws;                  // [SEQ][3840]
    unsigned short* attn_bf   = qkv_bf    + (size_t)SEQ * QKV_N;        // [SEQ][1280]
    unsigned short* hidden_bf = attn_bf   + (size_t)SEQ * DIM;          // [SEQ][1280]
    unsigned short* qkvw_bf   = hidden_bf + (size_t)SEQ * DIM;          // [3840][1280]
    unsigned short* projw_bf  = qkvw_bf   + (size_t)QKV_N * DIM;        // [1280][1280]

    // 0) f32 -> bf16 converts
    {
        const long n0 = (long)SEQ * DIM;
        const long n1 = (long)QKV_N * DIM;
        const long n2 = (long)DIM * DIM;
        cvt_f32_bf16<<<(int)(n0 / (8 * 256)), 256, 0, stream>>>(hidden, hidden_bf, n0);
        cvt_f32_bf16<<<(int)(n1 / (8 * 256)), 256, 0, stream>>>(qkv_w, qkvw_bf, n1);
        cvt_f32_bf16<<<(int)(n2 / (8 * 256)), 256, 0, stream>>>(proj_w, projw_bf, n2);
    }
    // 1) QKV projection (bf16 MFMA), bf16 out
    {
        dim3 grid(QKV_N / 128, SEQ / 128);
        gemm_nt_bf16<1><<<grid, 256, 0, stream>>>(hidden_bf, qkvw_bf, qkv_b,
                                                  (void*)qkv_bf, SEQ, QKV_N, DIM);
    }
    // 2) windowed attention (RoPE fused)
    {
        dim3 grid(NHEAD, NWIN);
        win_attn<<<grid, 256, 0, stream>>>(qkv_bf, cosb, sinb, masks, attn_bf);
    }
    // 3) output projection (bf16 MFMA), f32 out
    {
        dim3 grid(DIM / 128, SEQ / 128);
        gemm_nt_bf16<0><<<grid, 256, 0, stream>>>(attn_bf, projw_bf, proj_b,
                                                  (void*)out, SEQ, DIM, DIM);
    }
}

// Round 3
// 410.283 us; speedup vs baseline: 8.6592x; 1.8293x over previous
//
#include <hip/hip_runtime.h>
#include <hip/hip_bf16.h>

#define SEQ 16384
#define DIM 1280
#define NHEAD 16
#define HD 80
#define NWIN 256   // SEQ / 64
#define QKV_N 3840 // 3 * DIM

typedef __attribute__((ext_vector_type(8))) short bf16x8;
typedef __attribute__((ext_vector_type(8))) unsigned short ushort8;
typedef __attribute__((ext_vector_type(4))) float f32x4;

__device__ inline unsigned short f2bf(float x) {
    union { __hip_bfloat16 b; unsigned short u; } cv;
    cv.b = __float2bfloat16(x);
    return cv.u;
}
__device__ inline float bf2f(unsigned short u) {
    union { unsigned int i; float f; } cv;
    cv.i = ((unsigned int)u) << 16;
    return cv.f;
}

// async global->LDS, 16B per lane, wave-uniform LDS base + lane*16
#define GLD16(g, l) __builtin_amdgcn_global_load_lds( \
    (const __attribute__((address_space(1))) void*)(g), \
    (__attribute__((address_space(3))) void*)(l), 16, 0, 0)

// ---------------------------------------------------------------------------
// f32 -> bf16 convert, 8 elems/thread, vectorized
// ---------------------------------------------------------------------------
__global__ __launch_bounds__(256) void cvt_f32_bf16(const float* __restrict__ src,
                                                    unsigned short* __restrict__ dst,
                                                    long n) {
    long i = ((long)blockIdx.x * 256 + threadIdx.x) * 8;
    if (i >= n) return;
    const float4 a = *(const float4*)(src + i);
    const float4 b = *(const float4*)(src + i + 4);
    ushort8 o;
    o[0] = f2bf(a.x); o[1] = f2bf(a.y); o[2] = f2bf(a.z); o[3] = f2bf(a.w);
    o[4] = f2bf(b.x); o[5] = f2bf(b.y); o[6] = f2bf(b.z); o[7] = f2bf(b.w);
    *(ushort8*)(dst + i) = o;
}

// ---------------------------------------------------------------------------
// bf16 MFMA NT-GEMM: out[M][N] = A[M][K] @ B[N][K]^T + bias
// 128x128 tile, BK=32, 256 threads (4 waves, 2x2), mfma_f32_16x16x32_bf16
// ---------------------------------------------------------------------------
template <int OUT_BF16>
__global__ __launch_bounds__(256) void gemm_nt_bf16(
    const unsigned short* __restrict__ A,   // [M][K] bf16
    const unsigned short* __restrict__ B,   // [N][K] bf16
    const float* __restrict__ bias,         // [N]
    void* __restrict__ outp,                // [M][N] f32 or bf16
    int M, int N, int K)
{
    __shared__ unsigned short As[128 * 32];
    __shared__ unsigned short Bs[128 * 32];

    const int t = threadIdx.x;
    const int lane = t & 63;
    const int bm = blockIdx.y * 128;
    const int bn = blockIdx.x * 128;
    const int wave = t >> 6;
    const int wr = (wave >> 1) * 64;
    const int wc = (wave & 1) * 64;

    const int r0 = t >> 2;
    const int koff = (t & 3) * 8;
    const unsigned short* ga0 = A + (size_t)(bm + r0) * K + koff;
    const unsigned short* ga1 = A + (size_t)(bm + r0 + 64) * K + koff;
    const unsigned short* gb0 = B + (size_t)(bn + r0) * K + koff;
    const unsigned short* gb1 = B + (size_t)(bn + r0 + 64) * K + koff;

    unsigned short* lA0 = As + (t & ~63) * 8;
    unsigned short* lA1 = lA0 + 2048;
    unsigned short* lB0 = Bs + (t & ~63) * 8;
    unsigned short* lB1 = lB0 + 2048;

    const int row16 = lane & 15;
    const int kb8 = (lane >> 4) * 8;
    const unsigned short* pa = As + (wr + row16) * 32 + kb8;
    const unsigned short* pb = Bs + (wc + row16) * 32 + kb8;

    f32x4 acc[4][4];
#pragma unroll
    for (int m = 0; m < 4; ++m)
#pragma unroll
        for (int n = 0; n < 4; ++n)
            acc[m][n] = (f32x4){0.f, 0.f, 0.f, 0.f};

    for (int k0 = 0; k0 < K; k0 += 32) {
        __syncthreads();
        GLD16(ga0 + k0, lA0);
        GLD16(ga1 + k0, lA1);
        GLD16(gb0 + k0, lB0);
        GLD16(gb1 + k0, lB1);
        __syncthreads();

        bf16x8 af[4], bfr[4];
#pragma unroll
        for (int m = 0; m < 4; ++m) af[m] = *(const bf16x8*)(pa + m * 512);
#pragma unroll
        for (int n = 0; n < 4; ++n) bfr[n] = *(const bf16x8*)(pb + n * 512);
#pragma unroll
        for (int m = 0; m < 4; ++m)
#pragma unroll
            for (int n = 0; n < 4; ++n)
                acc[m][n] = __builtin_amdgcn_mfma_f32_16x16x32_bf16(
                    af[m], bfr[n], acc[m][n], 0, 0, 0);
    }

    const int or0 = bm + wr + (lane >> 4) * 4;
    const int oc0 = bn + wc + row16;
    float bv[4];
#pragma unroll
    for (int n = 0; n < 4; ++n) bv[n] = bias[oc0 + n * 16];
#pragma unroll
    for (int m = 0; m < 4; ++m)
#pragma unroll
        for (int n = 0; n < 4; ++n)
#pragma unroll
            for (int r = 0; r < 4; ++r) {
                const int row = or0 + m * 16 + r;
                const int col = oc0 + n * 16;
                const float v = acc[m][n][r] + bv[n];
                if (OUT_BF16)
                    ((unsigned short*)outp)[(size_t)row * N + col] = f2bf(v);
                else
                    ((float*)outp)[(size_t)row * N + col] = v;
            }
}

// ---------------------------------------------------------------------------
// MFMA windowed attention. One block per (head, window), 4 waves cooperate.
// Stages Q,K (RoPE fused, K-dim padded 80->96 with zeros) and V^T in LDS
// as bf16; QK^T + in-register softmax (16-lane shuffle reduce) + PV via
// mfma_f32_16x16x32_bf16. P (bf16) reuses the Q LDS region.
// LDS strides: Q/K 104 (208B, 16B-aligned, 2-way), Vt 88 (176B, 2-way),
// P 72 (144B, 2-way). Total 39.75 KB -> 4 blocks/CU.
// ---------------------------------------------------------------------------
__global__ __launch_bounds__(256) void win_attn_mfma(
    const unsigned short* __restrict__ qkv,  // [S][3840] bf16
    const float* __restrict__ cosb,          // [S][80]
    const float* __restrict__ sinb,          // [S][80]
    const float* __restrict__ mask,          // [NWIN][64][64]
    unsigned short* __restrict__ attn_out)   // [S][1280] bf16
{
    const int h = blockIdx.x;
    const int win = blockIdx.y;
    const int t = threadIdx.x;
    const int w = t >> 6;       // wave id: output rows [16w, 16w+16)
    const int lane = t & 63;
    const int l15 = lane & 15;
    const int g = lane >> 4;

    __shared__ unsigned short Qs[64 * 104];
    __shared__ unsigned short Ks[64 * 104];
    __shared__ unsigned short Vt[80 * 88];
    unsigned short* P = Qs;     // reuse after QK^T (barrier-protected)

    const float scale = 0.11180339887498949f;  // 1/sqrt(80)

    // ---- stage Q,K with fused RoPE (640 pair-chunks: 2 tiles x 64 tok x 5) --
    for (int c = t; c < 640; c += 256) {
        const int qk = c / 320;           // 0 = q, 1 = k  (wave-uniform)
        const int cc = c % 320;
        const int tok = cc / 5;
        const int dd = (cc % 5) * 8;      // d in [0,40)
        const int tokg = win * 64 + tok;
        const size_t gb = (size_t)tokg * QKV_N + h * HD + qk * DIM;
        const bf16x8 lo = *(const bf16x8*)(qkv + gb + dd);
        const bf16x8 hi = *(const bf16x8*)(qkv + gb + dd + 40);
        float cl[8], sl[8], ch[8], sh[8];
        *(float4*)cl = *(const float4*)(cosb + tokg * HD + dd);
        *(float4*)(cl + 4) = *(const float4*)(cosb + tokg * HD + dd + 4);
        *(float4*)sl = *(const float4*)(sinb + tokg * HD + dd);
        *(float4*)(sl + 4) = *(const float4*)(sinb + tokg * HD + dd + 4);
        *(float4*)ch = *(const float4*)(cosb + tokg * HD + dd + 40);
        *(float4*)(ch + 4) = *(const float4*)(cosb + tokg * HD + dd + 44);
        *(float4*)sh = *(const float4*)(sinb + tokg * HD + dd + 40);
        *(float4*)(sh + 4) = *(const float4*)(sinb + tokg * HD + dd + 44);
        ushort8 olo, ohi;
#pragma unroll
        for (int j = 0; j < 8; ++j) {
            const float x1 = bf2f((unsigned short)lo[j]);
            const float x2 = bf2f((unsigned short)hi[j]);
            float rl = x1 * cl[j] - x2 * sl[j];
            float rh = x2 * ch[j] + x1 * sh[j];
            if (qk == 0) { rl *= scale; rh *= scale; }
            olo[j] = f2bf(rl);
            ohi[j] = f2bf(rh);
        }
        unsigned short* base = (qk ? Ks : Qs) + tok * 104 + dd;
        *(ushort8*)base = olo;
        *(ushort8*)(base + 40) = ohi;
    }
    // zero-pad k = 80..96 (one 16B chunk per thread)
    {
        const int tile = t >> 7, row = (t >> 1) & 63, half = t & 1;
        ushort8 z = (ushort8)0;
        *(ushort8*)((tile ? Ks : Qs) + row * 104 + 80 + half * 8) = z;
    }
    // ---- stage V^T ----
    for (int c = t; c < 640; c += 256) {
        const int tok = c / 10;
        const int dd = (c % 10) * 8;
        const bf16x8 vv = *(const bf16x8*)(qkv +
            (size_t)(win * 64 + tok) * QKV_N + h * HD + 2 * DIM + dd);
#pragma unroll
        for (int j = 0; j < 8; ++j)
            Vt[(dd + j) * 88 + tok] = (unsigned short)vv[j];
    }
    __syncthreads();

    // ---- QK^T: wave w computes score rows [16w,16w+16) x all 64 cols ----
    f32x4 acc[4];
#pragma unroll
    for (int n = 0; n < 4; ++n) acc[n] = (f32x4){0.f, 0.f, 0.f, 0.f};
#pragma unroll
    for (int ks = 0; ks < 3; ++ks) {
        const int k0 = ks * 32;
        const bf16x8 af = *(const bf16x8*)(Qs + (w * 16 + l15) * 104 + k0 + g * 8);
#pragma unroll
        for (int n = 0; n < 4; ++n) {
            const bf16x8 bfr = *(const bf16x8*)(Ks + (n * 16 + l15) * 104 + k0 + g * 8);
            acc[n] = __builtin_amdgcn_mfma_f32_16x16x32_bf16(af, bfr, acc[n], 0, 0, 0);
        }
    }

    // ---- mask + softmax (rows g*4+r, cols n*16+l15; reduce over 16 lanes) --
    const float* mp = mask + (size_t)win * 4096;
    float pr[4][4];
#pragma unroll
    for (int r = 0; r < 4; ++r) {
        const int row = w * 16 + g * 4 + r;
        float v[4];
#pragma unroll
        for (int n = 0; n < 4; ++n)
            v[n] = acc[n][r] + mp[row * 64 + n * 16 + l15];
        float mx = fmaxf(fmaxf(v[0], v[1]), fmaxf(v[2], v[3]));
        mx = fmaxf(mx, __shfl_xor(mx, 1));
        mx = fmaxf(mx, __shfl_xor(mx, 2));
        mx = fmaxf(mx, __shfl_xor(mx, 4));
        mx = fmaxf(mx, __shfl_xor(mx, 8));
        float sum = 0.f;
#pragma unroll
        for (int n = 0; n < 4; ++n) { v[n] = __expf(v[n] - mx); sum += v[n]; }
        sum += __shfl_xor(sum, 1);
        sum += __shfl_xor(sum, 2);
        sum += __shfl_xor(sum, 4);
        sum += __shfl_xor(sum, 8);
        const float inv = 1.0f / sum;
#pragma unroll
        for (int n = 0; n < 4; ++n) pr[r][n] = v[n] * inv;
    }

    __syncthreads();   // all waves done reading Qs before P overwrites it
#pragma unroll
    for (int r = 0; r < 4; ++r)
#pragma unroll
        for (int n = 0; n < 4; ++n)
            P[(w * 16 + g * 4 + r) * 72 + n * 16 + l15] = f2bf(pr[r][n]);
    __syncthreads();

    // ---- PV: out rows [16w,16w+16) x 80 cols ----
    f32x4 ao[5];
#pragma unroll
    for (int n = 0; n < 5; ++n) ao[n] = (f32x4){0.f, 0.f, 0.f, 0.f};
#pragma unroll
    for (int ks = 0; ks < 2; ++ks) {
        const int k0 = ks * 32;
        const bf16x8 pa = *(const bf16x8*)(P + (w * 16 + l15) * 72 + k0 + g * 8);
#pragma unroll
        for (int n = 0; n < 5; ++n) {
            const bf16x8 bv = *(const bf16x8*)(Vt + (n * 16 + l15) * 88 + k0 + g * 8);
            ao[n] = __builtin_amdgcn_mfma_f32_16x16x32_bf16(pa, bv, ao[n], 0, 0, 0);
        }
    }

    // ---- epilogue ----
#pragma unroll
    for (int n = 0; n < 5; ++n)
#pragma unroll
        for (int r = 0; r < 4; ++r) {
            const int row = win * 64 + w * 16 + g * 4 + r;
            attn_out[(size_t)row * DIM + h * HD + n * 16 + l15] = f2bf(ao[n][r]);
        }
}

// ---------------------------------------------------------------------------
extern "C" void kernel_launch(void* const* d_in, const int* in_sizes, int n_in,
                              void* d_out, int out_size, void* d_ws, size_t ws_size,
                              hipStream_t stream) {
    const float* hidden = (const float*)d_in[0];
    const float* masks  = (const float*)d_in[1];
    const float* cosb   = (const float*)d_in[2];
    const float* sinb   = (const float*)d_in[3];
    const float* qkv_w  = (const float*)d_in[4];
    const float* qkv_b  = (const float*)d_in[5];
    const float* proj_w = (const float*)d_in[6];
    const float* proj_b = (const float*)d_in[7];
    float* out = (float*)d_out;

    unsigned short* qkv_bf    = (unsigned short*)d_ws;                  // [SEQ][3840]
    unsigned short* attn_bf   = qkv_bf    + (size_t)SEQ * QKV_N;        // [SEQ][1280]
    unsigned short* hidden_bf = attn_bf   + (size_t)SEQ * DIM;          // [SEQ][1280]
    unsigned short* qkvw_bf   = hidden_bf + (size_t)SEQ * DIM;          // [3840][1280]
    unsigned short* projw_bf  = qkvw_bf   + (size_t)QKV_N * DIM;        // [1280][1280]

    {
        const long n0 = (long)SEQ * DIM;
        const long n1 = (long)QKV_N * DIM;
        const long n2 = (long)DIM * DIM;
        cvt_f32_bf16<<<(int)(n0 / (8 * 256)), 256, 0, stream>>>(hidden, hidden_bf, n0);
        cvt_f32_bf16<<<(int)(n1 / (8 * 256)), 256, 0, stream>>>(qkv_w, qkvw_bf, n1);
        cvt_f32_bf16<<<(int)(n2 / (8 * 256)), 256, 0, stream>>>(proj_w, projw_bf, n2);
    }
    {
        dim3 grid(QKV_N / 128, SEQ / 128);
        gemm_nt_bf16<1><<<grid, 256, 0, stream>>>(hidden_bf, qkvw_bf, qkv_b,
                                                  (void*)qkv_bf, SEQ, QKV_N, DIM);
    }
    {
        dim3 grid(NHEAD, NWIN);
        win_attn_mfma<<<grid, 256, 0, stream>>>(qkv_bf, cosb, sinb, masks, attn_bf);
    }
    {
        dim3 grid(DIM / 128, SEQ / 128);
        gemm_nt_bf16<0><<<grid, 256, 0, stream>>>(attn_bf, projw_bf, proj_b,
                                                  (void*)out, SEQ, DIM, DIM);
    }
}

// Round 5
// 342.995 us; speedup vs baseline: 10.3580x; 1.1962x over previous
//
#include <hip/hip_runtime.h>
#include <hip/hip_bf16.h>

#define SEQ 16384
#define DIM 1280
#define NHEAD 16
#define HD 80
#define NWIN 256   // SEQ / 64
#define QKV_N 3840 // 3 * DIM
#define GK 1280    // K of both GEMMs
#define NT 20      // GK / 64

typedef __attribute__((ext_vector_type(8))) short bf16x8;
typedef __attribute__((ext_vector_type(8))) unsigned short ushort8;
typedef __attribute__((ext_vector_type(4))) float f32x4;

__device__ inline unsigned short f2bf(float x) {
    union { __hip_bfloat16 b; unsigned short u; } cv;
    cv.b = __float2bfloat16(x);
    return cv.u;
}
__device__ inline float bf2f(unsigned short u) {
    union { unsigned int i; float f; } cv;
    cv.i = ((unsigned int)u) << 16;
    return cv.f;
}

// async global->LDS, 16B per lane, wave-uniform LDS base + lane*16
#define GLD16(g, l) __builtin_amdgcn_global_load_lds( \
    (const __attribute__((address_space(1))) void*)(g), \
    (__attribute__((address_space(3))) void*)(l), 16, 0, 0)

// ---------------------------------------------------------------------------
// f32 -> bf16 convert, 8 elems/thread, vectorized
// ---------------------------------------------------------------------------
__global__ __launch_bounds__(256) void cvt_f32_bf16(const float* __restrict__ src,
                                                    unsigned short* __restrict__ dst,
                                                    long n) {
    long i = ((long)blockIdx.x * 256 + threadIdx.x) * 8;
    if (i >= n) return;
    const float4 a = *(const float4*)(src + i);
    const float4 b = *(const float4*)(src + i + 4);
    ushort8 o;
    o[0] = f2bf(a.x); o[1] = f2bf(a.y); o[2] = f2bf(a.z); o[3] = f2bf(a.w);
    o[4] = f2bf(b.x); o[5] = f2bf(b.y); o[6] = f2bf(b.z); o[7] = f2bf(b.w);
    *(ushort8*)(dst + i) = o;
}

// ---------------------------------------------------------------------------
// Deep-pipelined bf16 MFMA NT-GEMM: out[M][N] = A[M][K] @ B[N][K]^T + bias
// 256x256 tile, BK=64, 512 threads (8 waves 2Mx4N, 128x64 out each).
// Counted vmcnt(8) keeps next tile's global_load_lds in flight across the
// barrier (T3/T4). LDS XOR-swizzle (T2): elem ^= ((row&7)<<3), applied as
// pre-swizzled GLOBAL source (linear LDS dest, rule #21) and on the ds_read
// k-offset — XOR applied to the FULL k offset (kk*32 + g*8), never added
// after (bit-5 collision was round-4's bug). setprio around MFMA (T5).
// XCD-aware block swizzle (T1, grid % 8 == 0).
// ---------------------------------------------------------------------------
template <int OUT_BF16>
__global__ __launch_bounds__(512, 2) void gemm_nt_bf16_dp(
    const unsigned short* __restrict__ A,   // [M][GK] bf16
    const unsigned short* __restrict__ B,   // [N][GK] bf16
    const float* __restrict__ bias,         // [N]
    void* __restrict__ outp,                // [M][N] f32 or bf16
    int N, int nbx)                         // nbx = N/256
{
    __shared__ unsigned short sh[65536];    // [2][A 16384 | B 16384], 128 KiB

    const int t = threadIdx.x;
    const int w = t >> 6;
    const int lane = t & 63;
    const int l15 = lane & 15;
    const int g = lane >> 4;

    // T1: XCD swizzle (gridDim.x multiple of 8)
    const int cpx = gridDim.x >> 3;
    const int bid = blockIdx.x;
    const int wg = (bid & 7) * cpx + (bid >> 3);
    const int bm = (wg / nbx) * 256;
    const int bn = (wg % nbx) * 256;

    const int wr = (w >> 2) * 128;   // wave rows [wr, wr+128)
    const int wc = (w & 3) * 64;     // wave cols [wc, wc+64)

    // ---- staging precompute (4 A-loads + 4 B-loads per thread per tile) ----
    // thread t covers LDS elems [t*8, t*8+8) of each 64-row block j:
    // row = t>>3 (within block), in-row slot = (t&7)*8.
    // Pre-swizzled source col: slot ^ ((row&7)<<3).
    const int tr = t >> 3;
    const int colsw = ((t & 7) * 8) ^ (((t >> 3) & 7) << 3);  // elements
    const unsigned short* gA[4];
    const unsigned short* gB[4];
#pragma unroll
    for (int j = 0; j < 4; ++j) {
        gA[j] = A + (size_t)(bm + j * 64 + tr) * GK + colsw;
        gB[j] = B + (size_t)(bn + j * 64 + tr) * GK + colsw;
    }
    const int wub = (t & ~63) * 8;   // wave-uniform LDS elem base (w*512)

    // ---- ds_read fragment offsets (elements), swizzled ----
    // LDS[row*64 + e] holds global[row][e ^ s], s = (row&7)<<3 = (l15&7)<<3.
    // Fragment for k-chunk kk reads e = (kk*32 + g*8) ^ s  (XOR of FULL offset).
    const int sw = (l15 & 7) << 3;
    const int fk0 = (g * 8) ^ sw;         // kk = 0
    const int fk1 = (32 + g * 8) ^ sw;    // kk = 1
    int arow[8], brow[4];
#pragma unroll
    for (int mi = 0; mi < 8; ++mi) arow[mi] = (wr + mi * 16 + l15) * 64;
#pragma unroll
    for (int ni = 0; ni < 4; ++ni) brow[ni] = 16384 + (wc + ni * 16 + l15) * 64;

    f32x4 acc[8][4];
#pragma unroll
    for (int mi = 0; mi < 8; ++mi)
#pragma unroll
        for (int ni = 0; ni < 4; ++ni)
            acc[mi][ni] = (f32x4){0.f, 0.f, 0.f, 0.f};

    auto STAGE = [&](int kt, int d) {
        const int kadv = kt * 64;
        unsigned short* dA = sh + d * 32768 + wub;
        unsigned short* dB = sh + d * 32768 + 16384 + wub;
#pragma unroll
        for (int j = 0; j < 4; ++j) {
            GLD16(gA[j] + kadv, dA + j * 4096);
            GLD16(gB[j] + kadv, dB + j * 4096);
        }
    };

    auto COMPUTE = [&](int d) {
        const unsigned short* base = sh + d * 32768;
#pragma unroll
        for (int kk = 0; kk < 2; ++kk) {
            const int fk = kk ? fk1 : fk0;
            bf16x8 af[8], bfr[4];
#pragma unroll
            for (int mi = 0; mi < 8; ++mi)
                af[mi] = *(const bf16x8*)(base + arow[mi] + fk);
#pragma unroll
            for (int ni = 0; ni < 4; ++ni)
                bfr[ni] = *(const bf16x8*)(base + brow[ni] + fk);
            __builtin_amdgcn_s_setprio(1);
#pragma unroll
            for (int mi = 0; mi < 8; ++mi)
#pragma unroll
                for (int ni = 0; ni < 4; ++ni)
                    acc[mi][ni] = __builtin_amdgcn_mfma_f32_16x16x32_bf16(
                        af[mi], bfr[ni], acc[mi][ni], 0, 0, 0);
            __builtin_amdgcn_s_setprio(0);
        }
    };

    // ---- pipeline ----
    STAGE(0, 0);
    for (int kt = 0; kt < NT - 1; ++kt) {
        STAGE(kt + 1, (kt + 1) & 1);
        asm volatile("s_waitcnt vmcnt(8)" ::: "memory");  // tile kt staged
        asm volatile("s_barrier" ::: "memory");
        COMPUTE(kt & 1);
        asm volatile("s_barrier" ::: "memory");           // buf[kt&1] free
    }
    asm volatile("s_waitcnt vmcnt(0)" ::: "memory");      // last tile staged
    asm volatile("s_barrier" ::: "memory");
    COMPUTE((NT - 1) & 1);

    // ---- epilogue: C/D layout col=l15, row=g*4+reg ----
    const int orow = bm + wr + g * 4;
    const int ocol = bn + wc + l15;
    float bv[4];
#pragma unroll
    for (int ni = 0; ni < 4; ++ni) bv[ni] = bias[ocol + ni * 16];
#pragma unroll
    for (int mi = 0; mi < 8; ++mi)
#pragma unroll
        for (int ni = 0; ni < 4; ++ni)
#pragma unroll
            for (int r = 0; r < 4; ++r) {
                const int row = orow + mi * 16 + r;
                const int col = ocol + ni * 16;
                const float v = acc[mi][ni][r] + bv[ni];
                if (OUT_BF16)
                    ((unsigned short*)outp)[(size_t)row * N + col] = f2bf(v);
                else
                    ((float*)outp)[(size_t)row * N + col] = v;
            }
}

// ---------------------------------------------------------------------------
// MFMA windowed attention (unchanged; ~55 us)
// ---------------------------------------------------------------------------
__global__ __launch_bounds__(256) void win_attn_mfma(
    const unsigned short* __restrict__ qkv,  // [S][3840] bf16
    const float* __restrict__ cosb,          // [S][80]
    const float* __restrict__ sinb,          // [S][80]
    const float* __restrict__ mask,          // [NWIN][64][64]
    unsigned short* __restrict__ attn_out)   // [S][1280] bf16
{
    const int h = blockIdx.x;
    const int win = blockIdx.y;
    const int t = threadIdx.x;
    const int w = t >> 6;
    const int lane = t & 63;
    const int l15 = lane & 15;
    const int g = lane >> 4;

    __shared__ unsigned short Qs[64 * 104];
    __shared__ unsigned short Ks[64 * 104];
    __shared__ unsigned short Vt[80 * 88];
    unsigned short* P = Qs;

    const float scale = 0.11180339887498949f;  // 1/sqrt(80)

    for (int c = t; c < 640; c += 256) {
        const int qk = c / 320;
        const int cc = c % 320;
        const int tok = cc / 5;
        const int dd = (cc % 5) * 8;
        const int tokg = win * 64 + tok;
        const size_t gb = (size_t)tokg * QKV_N + h * HD + qk * DIM;
        const bf16x8 lo = *(const bf16x8*)(qkv + gb + dd);
        const bf16x8 hi = *(const bf16x8*)(qkv + gb + dd + 40);
        float cl[8], sl[8], ch[8], sh[8];
        *(float4*)cl = *(const float4*)(cosb + tokg * HD + dd);
        *(float4*)(cl + 4) = *(const float4*)(cosb + tokg * HD + dd + 4);
        *(float4*)sl = *(const float4*)(sinb + tokg * HD + dd);
        *(float4*)(sl + 4) = *(const float4*)(sinb + tokg * HD + dd + 4);
        *(float4*)ch = *(const float4*)(cosb + tokg * HD + dd + 40);
        *(float4*)(ch + 4) = *(const float4*)(cosb + tokg * HD + dd + 44);
        *(float4*)sh = *(const float4*)(sinb + tokg * HD + dd + 40);
        *(float4*)(sh + 4) = *(const float4*)(sinb + tokg * HD + dd + 44);
        ushort8 olo, ohi;
#pragma unroll
        for (int j = 0; j < 8; ++j) {
            const float x1 = bf2f((unsigned short)lo[j]);
            const float x2 = bf2f((unsigned short)hi[j]);
            float rl = x1 * cl[j] - x2 * sl[j];
            float rh = x2 * ch[j] + x1 * sh[j];
            if (qk == 0) { rl *= scale; rh *= scale; }
            olo[j] = f2bf(rl);
            ohi[j] = f2bf(rh);
        }
        unsigned short* base = (qk ? Ks : Qs) + tok * 104 + dd;
        *(ushort8*)base = olo;
        *(ushort8*)(base + 40) = ohi;
    }
    {
        const int tile = t >> 7, row = (t >> 1) & 63, half = t & 1;
        ushort8 z = (ushort8)0;
        *(ushort8*)((tile ? Ks : Qs) + row * 104 + 80 + half * 8) = z;
    }
    for (int c = t; c < 640; c += 256) {
        const int tok = c / 10;
        const int dd = (c % 10) * 8;
        const bf16x8 vv = *(const bf16x8*)(qkv +
            (size_t)(win * 64 + tok) * QKV_N + h * HD + 2 * DIM + dd);
#pragma unroll
        for (int j = 0; j < 8; ++j)
            Vt[(dd + j) * 88 + tok] = (unsigned short)vv[j];
    }
    __syncthreads();

    f32x4 acc[4];
#pragma unroll
    for (int n = 0; n < 4; ++n) acc[n] = (f32x4){0.f, 0.f, 0.f, 0.f};
#pragma unroll
    for (int ks = 0; ks < 3; ++ks) {
        const int k0 = ks * 32;
        const bf16x8 af = *(const bf16x8*)(Qs + (w * 16 + l15) * 104 + k0 + g * 8);
#pragma unroll
        for (int n = 0; n < 4; ++n) {
            const bf16x8 bfr = *(const bf16x8*)(Ks + (n * 16 + l15) * 104 + k0 + g * 8);
            acc[n] = __builtin_amdgcn_mfma_f32_16x16x32_bf16(af, bfr, acc[n], 0, 0, 0);
        }
    }

    const float* mp = mask + (size_t)win * 4096;
    float pr[4][4];
#pragma unroll
    for (int r = 0; r < 4; ++r) {
        const int row = w * 16 + g * 4 + r;
        float v[4];
#pragma unroll
        for (int n = 0; n < 4; ++n)
            v[n] = acc[n][r] + mp[row * 64 + n * 16 + l15];
        float mx = fmaxf(fmaxf(v[0], v[1]), fmaxf(v[2], v[3]));
        mx = fmaxf(mx, __shfl_xor(mx, 1));
        mx = fmaxf(mx, __shfl_xor(mx, 2));
        mx = fmaxf(mx, __shfl_xor(mx, 4));
        mx = fmaxf(mx, __shfl_xor(mx, 8));
        float sum = 0.f;
#pragma unroll
        for (int n = 0; n < 4; ++n) { v[n] = __expf(v[n] - mx); sum += v[n]; }
        sum += __shfl_xor(sum, 1);
        sum += __shfl_xor(sum, 2);
        sum += __shfl_xor(sum, 4);
        sum += __shfl_xor(sum, 8);
        const float inv = 1.0f / sum;
#pragma unroll
        for (int n = 0; n < 4; ++n) pr[r][n] = v[n] * inv;
    }

    __syncthreads();
#pragma unroll
    for (int r = 0; r < 4; ++r)
#pragma unroll
        for (int n = 0; n < 4; ++n)
            P[(w * 16 + g * 4 + r) * 72 + n * 16 + l15] = f2bf(pr[r][n]);
    __syncthreads();

    f32x4 ao[5];
#pragma unroll
    for (int n = 0; n < 5; ++n) ao[n] = (f32x4){0.f, 0.f, 0.f, 0.f};
#pragma unroll
    for (int ks = 0; ks < 2; ++ks) {
        const int k0 = ks * 32;
        const bf16x8 pa = *(const bf16x8*)(P + (w * 16 + l15) * 72 + k0 + g * 8);
#pragma unroll
        for (int n = 0; n < 5; ++n) {
            const bf16x8 bv = *(const bf16x8*)(Vt + (n * 16 + l15) * 88 + k0 + g * 8);
            ao[n] = __builtin_amdgcn_mfma_f32_16x16x32_bf16(pa, bv, ao[n], 0, 0, 0);
        }
    }

#pragma unroll
    for (int n = 0; n < 5; ++n)
#pragma unroll
        for (int r = 0; r < 4; ++r) {
            const int row = win * 64 + w * 16 + g * 4 + r;
            attn_out[(size_t)row * DIM + h * HD + n * 16 + l15] = f2bf(ao[n][r]);
        }
}

// ---------------------------------------------------------------------------
extern "C" void kernel_launch(void* const* d_in, const int* in_sizes, int n_in,
                              void* d_out, int out_size, void* d_ws, size_t ws_size,
                              hipStream_t stream) {
    const float* hidden = (const float*)d_in[0];
    const float* masks  = (const float*)d_in[1];
    const float* cosb   = (const float*)d_in[2];
    const float* sinb   = (const float*)d_in[3];
    const float* qkv_w  = (const float*)d_in[4];
    const float* qkv_b  = (const float*)d_in[5];
    const float* proj_w = (const float*)d_in[6];
    const float* proj_b = (const float*)d_in[7];
    float* out = (float*)d_out;

    unsigned short* qkv_bf    = (unsigned short*)d_ws;                  // [SEQ][3840]
    unsigned short* attn_bf   = qkv_bf    + (size_t)SEQ * QKV_N;        // [SEQ][1280]
    unsigned short* hidden_bf = attn_bf   + (size_t)SEQ * DIM;          // [SEQ][1280]
    unsigned short* qkvw_bf   = hidden_bf + (size_t)SEQ * DIM;          // [3840][1280]
    unsigned short* projw_bf  = qkvw_bf   + (size_t)QKV_N * DIM;        // [1280][1280]

    {
        const long n0 = (long)SEQ * DIM;
        const long n1 = (long)QKV_N * DIM;
        const long n2 = (long)DIM * DIM;
        cvt_f32_bf16<<<(int)(n0 / (8 * 256)), 256, 0, stream>>>(hidden, hidden_bf, n0);
        cvt_f32_bf16<<<(int)(n1 / (8 * 256)), 256, 0, stream>>>(qkv_w, qkvw_bf, n1);
        cvt_f32_bf16<<<(int)(n2 / (8 * 256)), 256, 0, stream>>>(proj_w, projw_bf, n2);
    }
    {   // QKV projection: M=16384, N=3840 -> 64x15 = 960 blocks (%8==0)
        gemm_nt_bf16_dp<1><<<dim3(960), 512, 0, stream>>>(
            hidden_bf, qkvw_bf, qkv_b, (void*)qkv_bf, QKV_N, QKV_N / 256);
    }
    {
        dim3 grid(NHEAD, NWIN);
        win_attn_mfma<<<grid, 256, 0, stream>>>(qkv_bf, cosb, sinb, masks, attn_bf);
    }
    {   // output projection: M=16384, N=1280 -> 64x5 = 320 blocks (%8==0)
        gemm_nt_bf16_dp<0><<<dim3(320), 512, 0, stream>>>(
            attn_bf, projw_bf, proj_b, (void*)out, DIM, DIM / 256);
    }
}

// Round 6
// 327.275 us; speedup vs baseline: 10.8555x; 1.0480x over previous
//
#include <hip/hip_runtime.h>
#include <hip/hip_bf16.h>

#define SEQ 16384
#define DIM 1280
#define NHEAD 16
#define HD 80
#define NWIN 256   // SEQ / 64
#define QKV_N 3840 // 3 * DIM
#define GK 1280    // K of both GEMMs
#define NT 20      // GK / 64

typedef __attribute__((ext_vector_type(8))) short bf16x8;
typedef __attribute__((ext_vector_type(8))) unsigned short ushort8;
typedef __attribute__((ext_vector_type(4))) float f32x4;

__device__ inline unsigned short f2bf(float x) {
    union { __hip_bfloat16 b; unsigned short u; } cv;
    cv.b = __float2bfloat16(x);
    return cv.u;
}
__device__ inline float bf2f(unsigned short u) {
    union { unsigned int i; float f; } cv;
    cv.i = ((unsigned int)u) << 16;
    return cv.f;
}

// async global->LDS, 16B per lane, wave-uniform LDS base + lane*16
#define GLD16(g, l) __builtin_amdgcn_global_load_lds( \
    (const __attribute__((address_space(1))) void*)(g), \
    (__attribute__((address_space(3))) void*)(l), 16, 0, 0)

#define SBAR() asm volatile("s_barrier" ::: "memory")

// ---------------------------------------------------------------------------
// f32 -> bf16 convert, 8 elems/thread, vectorized
// ---------------------------------------------------------------------------
__global__ __launch_bounds__(256) void cvt_f32_bf16(const float* __restrict__ src,
                                                    unsigned short* __restrict__ dst,
                                                    long n) {
    long i = ((long)blockIdx.x * 256 + threadIdx.x) * 8;
    if (i >= n) return;
    const float4 a = *(const float4*)(src + i);
    const float4 b = *(const float4*)(src + i + 4);
    ushort8 o;
    o[0] = f2bf(a.x); o[1] = f2bf(a.y); o[2] = f2bf(a.z); o[3] = f2bf(a.w);
    o[4] = f2bf(b.x); o[5] = f2bf(b.y); o[6] = f2bf(b.z); o[7] = f2bf(b.w);
    *(ushort8*)(dst + i) = o;
}

// ---------------------------------------------------------------------------
// 8-phase bf16 MFMA NT-GEMM: out[M][N] = A[M][K] @ B[N][K]^T + bias
// 256x256 tile, BK=64, 512 threads (8 waves 2Mx4N, 128x64 out each).
// Per K-tile: 4 phases = (mi-half h, kk). Each phase: {ds_read frags,
// issue one 2-load stage unit, barrier, 16 MFMA (setprio), barrier}.
// Stage units: u0={A j0,j2} u1={A j1,j3} u2={B j0,j1} u3={B j2,j3};
// unit placement: q0->u1(kt+1), q1->u2(kt+1), q2->u3(kt+1), q3->u0(kt+2).
// Single vmcnt(2) at q3 drains tile kt+1 (kt+2's u0 stays in flight).
// Race-freedom: q3's u0(kt+2) write-set A{j0,j2} of the CURRENT region is
// disjoint from q3's read-set A{j1,j3}; A{j0,j2} reads (q0,q2) retired via
// lgkmcnt-before-MFMA + trailing barriers. B of region d^1 last read at
// tile kt-1, behind >=2 barriers. T1 XCD swizzle; T2 XOR swizzle (elem ^=
// (row&7)<<3, XOR of the FULL k-offset); T5 setprio.
// ---------------------------------------------------------------------------
template <int OUT_BF16>
__global__ __launch_bounds__(512, 2) void gemm_nt_bf16_8p(
    const unsigned short* __restrict__ A,   // [M][GK] bf16
    const unsigned short* __restrict__ B,   // [N][GK] bf16
    const float* __restrict__ bias,         // [N]
    void* __restrict__ outp,                // [M][N] f32 or bf16
    int N, int nbx)                         // nbx = N/256
{
    __shared__ unsigned short sh[65536];    // [2][A 16384 | B 16384], 128 KiB

    const int t = threadIdx.x;
    const int w = t >> 6;
    const int lane = t & 63;
    const int l15 = lane & 15;
    const int g = lane >> 4;

    // T1: XCD swizzle (gridDim.x multiple of 8)
    const int cpx = gridDim.x >> 3;
    const int bid = blockIdx.x;
    const int wg = (bid & 7) * cpx + (bid >> 3);
    const int bm = (wg / nbx) * 256;
    const int bn = (wg % nbx) * 256;

    const int wr = (w >> 2) * 128;   // wave rows [wr, wr+128)
    const int wc = (w & 3) * 64;     // wave cols [wc, wc+64)

    // staging: thread t covers 16B chunk (row = t>>3 within 64-row block j,
    // slot = t&7); pre-swizzled source col = slot*8 ^ ((row&7)<<3)
    const int tr = t >> 3;
    const int colsw = ((t & 7) * 8) ^ (((t >> 3) & 7) << 3);  // elements
    const unsigned short* gA[4];
    const unsigned short* gB[4];
#pragma unroll
    for (int j = 0; j < 4; ++j) {
        gA[j] = A + (size_t)(bm + j * 64 + tr) * GK + colsw;
        gB[j] = B + (size_t)(bn + j * 64 + tr) * GK + colsw;
    }
    const int wub = (t & ~63) * 8;   // wave-uniform LDS elem base

    // ds_read frag offsets: LDS[row*64 + e] = global[row][e ^ ((row&7)<<3)]
    // fragment k-chunk kk reads e = (kk*32 + g*8) ^ sw  (XOR of FULL offset)
    const int sw = (l15 & 7) << 3;
    const int fk0 = (g * 8) ^ sw;
    const int fk1 = (32 + g * 8) ^ sw;
    int arow[8], brow[4];
#pragma unroll
    for (int mi = 0; mi < 8; ++mi) arow[mi] = (wr + mi * 16 + l15) * 64;
#pragma unroll
    for (int ni = 0; ni < 4; ++ni) brow[ni] = 16384 + (wc + ni * 16 + l15) * 64;

    f32x4 acc[8][4];
#pragma unroll
    for (int mi = 0; mi < 8; ++mi)
#pragma unroll
        for (int ni = 0; ni < 4; ++ni)
            acc[mi][ni] = (f32x4){0.f, 0.f, 0.f, 0.f};

    // stage unit: 2 global_load_lds of unit u for K-tile `tile` -> region tile&1
    auto stageU = [&](int u, int tile) {
        if (tile >= NT) return;
        unsigned short* rg = sh + (tile & 1) * 32768 + wub;
        const int ka = tile * 64;
        if (u == 0) { GLD16(gA[0] + ka, rg);               GLD16(gA[2] + ka, rg + 8192); }
        if (u == 1) { GLD16(gA[1] + ka, rg + 4096);        GLD16(gA[3] + ka, rg + 12288); }
        if (u == 2) { GLD16(gB[0] + ka, rg + 16384);       GLD16(gB[1] + ka, rg + 20480); }
        if (u == 3) { GLD16(gB[2] + ka, rg + 24576);       GLD16(gB[3] + ka, rg + 28672); }
    };

    // ---- prologue: tile 0 fully + u0 of tile 1; drain tile 0 ----
    stageU(0, 0); stageU(1, 0); stageU(2, 0); stageU(3, 0);
    stageU(0, 1);
    asm volatile("s_waitcnt vmcnt(2)" ::: "memory");
    SBAR();

    bf16x8 af[4], bfr[4];

#define MFMA_QUAD(H)                                                          \
    __builtin_amdgcn_s_setprio(1);                                            \
    _Pragma("unroll") for (int mi = 0; mi < 4; ++mi)                          \
    _Pragma("unroll") for (int ni = 0; ni < 4; ++ni)                          \
        acc[(H) * 4 + mi][ni] = __builtin_amdgcn_mfma_f32_16x16x32_bf16(      \
            af[mi], bfr[ni], acc[(H) * 4 + mi][ni], 0, 0, 0);                 \
    __builtin_amdgcn_s_setprio(0);

    for (int kt = 0; kt < NT; ++kt) {
        const unsigned short* base = sh + (kt & 1) * 32768;

        // ---- phase q0: (h=0, kk=0) ----
#pragma unroll
        for (int ni = 0; ni < 4; ++ni) bfr[ni] = *(const bf16x8*)(base + brow[ni] + fk0);
#pragma unroll
        for (int mi = 0; mi < 4; ++mi) af[mi] = *(const bf16x8*)(base + arow[mi] + fk0);
        stageU(1, kt + 1);
        SBAR();
        MFMA_QUAD(0);
        SBAR();

        // ---- phase q1: (h=1, kk=0), reuse bfr ----
#pragma unroll
        for (int mi = 0; mi < 4; ++mi) af[mi] = *(const bf16x8*)(base + arow[4 + mi] + fk0);
        stageU(2, kt + 1);
        SBAR();
        MFMA_QUAD(1);
        SBAR();

        // ---- phase q2: (h=0, kk=1) ----
#pragma unroll
        for (int ni = 0; ni < 4; ++ni) bfr[ni] = *(const bf16x8*)(base + brow[ni] + fk1);
#pragma unroll
        for (int mi = 0; mi < 4; ++mi) af[mi] = *(const bf16x8*)(base + arow[mi] + fk1);
        stageU(3, kt + 1);
        SBAR();
        MFMA_QUAD(0);
        SBAR();

        // ---- phase q3: (h=1, kk=1), reuse bfr ----
#pragma unroll
        for (int mi = 0; mi < 4; ++mi) af[mi] = *(const bf16x8*)(base + arow[4 + mi] + fk1);
        stageU(0, kt + 2);
        if (kt < NT - 2)
            asm volatile("s_waitcnt vmcnt(2)" ::: "memory");   // tile kt+1 staged
        else if (kt == NT - 2)
            asm volatile("s_waitcnt vmcnt(0)" ::: "memory");   // last tile staged
        SBAR();
        MFMA_QUAD(1);
        SBAR();
    }
#undef MFMA_QUAD

    // ---- epilogue: C/D layout col=l15, row=g*4+reg ----
    const int orow = bm + wr + g * 4;
    const int ocol = bn + wc + l15;
    float bv[4];
#pragma unroll
    for (int ni = 0; ni < 4; ++ni) bv[ni] = bias[ocol + ni * 16];
#pragma unroll
    for (int mi = 0; mi < 8; ++mi)
#pragma unroll
        for (int ni = 0; ni < 4; ++ni)
#pragma unroll
            for (int r = 0; r < 4; ++r) {
                const int row = orow + mi * 16 + r;
                const int col = ocol + ni * 16;
                const float v = acc[mi][ni][r] + bv[ni];
                if (OUT_BF16)
                    ((unsigned short*)outp)[(size_t)row * N + col] = f2bf(v);
                else
                    ((float*)outp)[(size_t)row * N + col] = v;
            }
}

// ---------------------------------------------------------------------------
// MFMA windowed attention (unchanged; ~55 us)
// ---------------------------------------------------------------------------
__global__ __launch_bounds__(256) void win_attn_mfma(
    const unsigned short* __restrict__ qkv,  // [S][3840] bf16
    const float* __restrict__ cosb,          // [S][80]
    const float* __restrict__ sinb,          // [S][80]
    const float* __restrict__ mask,          // [NWIN][64][64]
    unsigned short* __restrict__ attn_out)   // [S][1280] bf16
{
    const int h = blockIdx.x;
    const int win = blockIdx.y;
    const int t = threadIdx.x;
    const int w = t >> 6;
    const int lane = t & 63;
    const int l15 = lane & 15;
    const int g = lane >> 4;

    __shared__ unsigned short Qs[64 * 104];
    __shared__ unsigned short Ks[64 * 104];
    __shared__ unsigned short Vt[80 * 88];
    unsigned short* P = Qs;

    const float scale = 0.11180339887498949f;  // 1/sqrt(80)

    for (int c = t; c < 640; c += 256) {
        const int qk = c / 320;
        const int cc = c % 320;
        const int tok = cc / 5;
        const int dd = (cc % 5) * 8;
        const int tokg = win * 64 + tok;
        const size_t gb = (size_t)tokg * QKV_N + h * HD + qk * DIM;
        const bf16x8 lo = *(const bf16x8*)(qkv + gb + dd);
        const bf16x8 hi = *(const bf16x8*)(qkv + gb + dd + 40);
        float cl[8], sl[8], ch[8], sh[8];
        *(float4*)cl = *(const float4*)(cosb + tokg * HD + dd);
        *(float4*)(cl + 4) = *(const float4*)(cosb + tokg * HD + dd + 4);
        *(float4*)sl = *(const float4*)(sinb + tokg * HD + dd);
        *(float4*)(sl + 4) = *(const float4*)(sinb + tokg * HD + dd + 4);
        *(float4*)ch = *(const float4*)(cosb + tokg * HD + dd + 40);
        *(float4*)(ch + 4) = *(const float4*)(cosb + tokg * HD + dd + 44);
        *(float4*)sh = *(const float4*)(sinb + tokg * HD + dd + 40);
        *(float4*)(sh + 4) = *(const float4*)(sinb + tokg * HD + dd + 44);
        ushort8 olo, ohi;
#pragma unroll
        for (int j = 0; j < 8; ++j) {
            const float x1 = bf2f((unsigned short)lo[j]);
            const float x2 = bf2f((unsigned short)hi[j]);
            float rl = x1 * cl[j] - x2 * sl[j];
            float rh = x2 * ch[j] + x1 * sh[j];
            if (qk == 0) { rl *= scale; rh *= scale; }
            olo[j] = f2bf(rl);
            ohi[j] = f2bf(rh);
        }
        unsigned short* base = (qk ? Ks : Qs) + tok * 104 + dd;
        *(ushort8*)base = olo;
        *(ushort8*)(base + 40) = ohi;
    }
    {
        const int tile = t >> 7, row = (t >> 1) & 63, half = t & 1;
        ushort8 z = (ushort8)0;
        *(ushort8*)((tile ? Ks : Qs) + row * 104 + 80 + half * 8) = z;
    }
    for (int c = t; c < 640; c += 256) {
        const int tok = c / 10;
        const int dd = (c % 10) * 8;
        const bf16x8 vv = *(const bf16x8*)(qkv +
            (size_t)(win * 64 + tok) * QKV_N + h * HD + 2 * DIM + dd);
#pragma unroll
        for (int j = 0; j < 8; ++j)
            Vt[(dd + j) * 88 + tok] = (unsigned short)vv[j];
    }
    __syncthreads();

    f32x4 acc[4];
#pragma unroll
    for (int n = 0; n < 4; ++n) acc[n] = (f32x4){0.f, 0.f, 0.f, 0.f};
#pragma unroll
    for (int ks = 0; ks < 3; ++ks) {
        const int k0 = ks * 32;
        const bf16x8 af = *(const bf16x8*)(Qs + (w * 16 + l15) * 104 + k0 + g * 8);
#pragma unroll
        for (int n = 0; n < 4; ++n) {
            const bf16x8 bfr = *(const bf16x8*)(Ks + (n * 16 + l15) * 104 + k0 + g * 8);
            acc[n] = __builtin_amdgcn_mfma_f32_16x16x32_bf16(af, bfr, acc[n], 0, 0, 0);
        }
    }

    const float* mp = mask + (size_t)win * 4096;
    float pr[4][4];
#pragma unroll
    for (int r = 0; r < 4; ++r) {
        const int row = w * 16 + g * 4 + r;
        float v[4];
#pragma unroll
        for (int n = 0; n < 4; ++n)
            v[n] = acc[n][r] + mp[row * 64 + n * 16 + l15];
        float mx = fmaxf(fmaxf(v[0], v[1]), fmaxf(v[2], v[3]));
        mx = fmaxf(mx, __shfl_xor(mx, 1));
        mx = fmaxf(mx, __shfl_xor(mx, 2));
        mx = fmaxf(mx, __shfl_xor(mx, 4));
        mx = fmaxf(mx, __shfl_xor(mx, 8));
        float sum = 0.f;
#pragma unroll
        for (int n = 0; n < 4; ++n) { v[n] = __expf(v[n] - mx); sum += v[n]; }
        sum += __shfl_xor(sum, 1);
        sum += __shfl_xor(sum, 2);
        sum += __shfl_xor(sum, 4);
        sum += __shfl_xor(sum, 8);
        const float inv = 1.0f / sum;
#pragma unroll
        for (int n = 0; n < 4; ++n) pr[r][n] = v[n] * inv;
    }

    __syncthreads();
#pragma unroll
    for (int r = 0; r < 4; ++r)
#pragma unroll
        for (int n = 0; n < 4; ++n)
            P[(w * 16 + g * 4 + r) * 72 + n * 16 + l15] = f2bf(pr[r][n]);
    __syncthreads();

    f32x4 ao[5];
#pragma unroll
    for (int n = 0; n < 5; ++n) ao[n] = (f32x4){0.f, 0.f, 0.f, 0.f};
#pragma unroll
    for (int ks = 0; ks < 2; ++ks) {
        const int k0 = ks * 32;
        const bf16x8 pa = *(const bf16x8*)(P + (w * 16 + l15) * 72 + k0 + g * 8);
#pragma unroll
        for (int n = 0; n < 5; ++n) {
            const bf16x8 bv = *(const bf16x8*)(Vt + (n * 16 + l15) * 88 + k0 + g * 8);
            ao[n] = __builtin_amdgcn_mfma_f32_16x16x32_bf16(pa, bv, ao[n], 0, 0, 0);
        }
    }

#pragma unroll
    for (int n = 0; n < 5; ++n)
#pragma unroll
        for (int r = 0; r < 4; ++r) {
            const int row = win * 64 + w * 16 + g * 4 + r;
            attn_out[(size_t)row * DIM + h * HD + n * 16 + l15] = f2bf(ao[n][r]);
        }
}

// ---------------------------------------------------------------------------
extern "C" void kernel_launch(void* const* d_in, const int* in_sizes, int n_in,
                              void* d_out, int out_size, void* d_ws, size_t ws_size,
                              hipStream_t stream) {
    const float* hidden = (const float*)d_in[0];
    const float* masks  = (const float*)d_in[1];
    const float* cosb   = (const float*)d_in[2];
    const float* sinb   = (const float*)d_in[3];
    const float* qkv_w  = (const float*)d_in[4];
    const float* qkv_b  = (const float*)d_in[5];
    const float* proj_w = (const float*)d_in[6];
    const float* proj_b = (const float*)d_in[7];
    float* out = (float*)d_out;

    unsigned short* qkv_bf    = (unsigned short*)d_ws;                  // [SEQ][3840]
    unsigned short* attn_bf   = qkv_bf    + (size_t)SEQ * QKV_N;        // [SEQ][1280]
    unsigned short* hidden_bf = attn_bf   + (size_t)SEQ * DIM;          // [SEQ][1280]
    unsigned short* qkvw_bf   = hidden_bf + (size_t)SEQ * DIM;          // [3840][1280]
    unsigned short* projw_bf  = qkvw_bf   + (size_t)QKV_N * DIM;        // [1280][1280]

    {
        const long n0 = (long)SEQ * DIM;
        const long n1 = (long)QKV_N * DIM;
        const long n2 = (long)DIM * DIM;
        cvt_f32_bf16<<<(int)(n0 / (8 * 256)), 256, 0, stream>>>(hidden, hidden_bf, n0);
        cvt_f32_bf16<<<(int)(n1 / (8 * 256)), 256, 0, stream>>>(qkv_w, qkvw_bf, n1);
        cvt_f32_bf16<<<(int)(n2 / (8 * 256)), 256, 0, stream>>>(proj_w, projw_bf, n2);
    }
    {   // QKV projection: M=16384, N=3840 -> 64x15 = 960 blocks (%8==0)
        gemm_nt_bf16_8p<1><<<dim3(960), 512, 0, stream>>>(
            hidden_bf, qkvw_bf, qkv_b, (void*)qkv_bf, QKV_N, QKV_N / 256);
    }
    {
        dim3 grid(NHEAD, NWIN);
        win_attn_mfma<<<grid, 256, 0, stream>>>(qkv_bf, cosb, sinb, masks, attn_bf);
    }
    {   // output projection: M=16384, N=1280 -> 64x5 = 320 blocks (%8==0)
        gemm_nt_bf16_8p<0><<<dim3(320), 512, 0, stream>>>(
            attn_bf, projw_bf, proj_b, (void*)out, DIM, DIM / 256);
    }
}